// Round 5
// baseline (764.269 us; speedup 1.0000x reference)
//
#include <hip/hip_runtime.h>
#include <stdint.h>

// ---------------------------------------------------------------------------
// GCN: agg1 = A_hat x (chunked XCD-pinned gather, + layer1 dropout-mask gen)
//      h    = relu+drop(agg1 W1 + b1)   (MFMA GEMM, mask from bitmask)
//      hw2  = h W2                      (MFMA GEMM, chunk-major C store)
//      out  = relu+drop(A_hat hw2 + b2) (chunked gather + threefry epilogue)
// Gather tables are stored chunk-major: Xc[8][M_PAD][32] bf16 — each 3.2MB
// chunk fits one XCD's 4MiB L2; blockIdx%8 pins chunk->XCD.
// ---------------------------------------------------------------------------

#define N_NODES 50000
#define N_EDGES 800000
#define M_PAD   50048   // 391 * 128
#define IN_C 256
#define HID_C 512
#define OUT_C 256
#define CH_STRIDE ((size_t)M_PAD * 32)   // ushorts per chunk

typedef __attribute__((ext_vector_type(8))) short bf16x8;
typedef __attribute__((ext_vector_type(4))) float f32x4;

struct U2 { unsigned a, b; };

__host__ __device__ constexpr unsigned rotl32(unsigned x, int d) {
  return (x << d) | (x >> (32 - d));
}

#define TF_ROUND(r) { x0 += x1; x1 = rotl32(x1, (r)); x1 ^= x0; }

__host__ __device__ constexpr U2 threefry2x32(unsigned k0, unsigned k1,
                                              unsigned x0, unsigned x1) {
  unsigned ks2 = k0 ^ k1 ^ 0x1BD11BDAu;
  x0 += k0; x1 += k1;
  TF_ROUND(13) TF_ROUND(15) TF_ROUND(26) TF_ROUND(6)  x0 += k1;  x1 += ks2 + 1u;
  TF_ROUND(17) TF_ROUND(29) TF_ROUND(16) TF_ROUND(24) x0 += ks2; x1 += k0 + 2u;
  TF_ROUND(13) TF_ROUND(15) TF_ROUND(26) TF_ROUND(6)  x0 += k0;  x1 += k1 + 3u;
  TF_ROUND(17) TF_ROUND(29) TF_ROUND(16) TF_ROUND(24) x0 += k1;  x1 += ks2 + 4u;
  TF_ROUND(13) TF_ROUND(15) TF_ROUND(26) TF_ROUND(6)  x0 += ks2; x1 += k0 + 5u;
  return U2{x0, x1};
}

__device__ __forceinline__ float drop_apply(float v, unsigned idx, unsigned k0, unsigned k1) {
  v = fmaxf(v, 0.f);
  U2 r = threefry2x32(k0, k1, 0u, idx);
  unsigned bits = r.a ^ r.b;
  return (bits >> 31) ? 0.f : v * 2.0f;
}

__device__ __forceinline__ ushort f2b(float f) {  // RTNE
  unsigned u = __builtin_bit_cast(unsigned, f);
  unsigned r = (u + 0x7fffu + ((u >> 16) & 1u)) >> 16;
  return (ushort)r;
}
__device__ __forceinline__ float b2f(ushort h) {
  unsigned u = (unsigned)h << 16;
  return __builtin_bit_cast(float, u);
}
__device__ __forceinline__ float b2f_hi(unsigned u) {  // high half of packed pair
  return __builtin_bit_cast(float, u & 0xffff0000u);
}
__device__ __forceinline__ float b2f_lo(unsigned u) {
  return __builtin_bit_cast(float, u << 16);
}

__device__ __forceinline__ void gload16(const void* g, void* l) {
  __builtin_amdgcn_global_load_lds(
      (const __attribute__((address_space(1))) void*)g,
      (__attribute__((address_space(3))) void*)l, 16, 0, 0);
}

// ---------------------------------------------------------------------------
// degree / dinv / scan / CSR build
// ---------------------------------------------------------------------------
__global__ void deg_kernel(const int* __restrict__ col, int* __restrict__ cnt, int E) {
  int e = blockIdx.x * 256 + threadIdx.x;
  if (e < E) atomicAdd(&cnt[col[e]], 1);
}

__global__ void dinv_kernel(const int* __restrict__ cnt, float* __restrict__ dinv, int N) {
  int n = blockIdx.x * 256 + threadIdx.x;
  if (n < N) dinv[n] = rsqrtf((float)cnt[n] + 1.0f);
}

__global__ __launch_bounds__(1024) void scan_local(const int* __restrict__ cnt,
                                                   int* __restrict__ indptr,
                                                   int* __restrict__ chunkSums, int n) {
  __shared__ int s[1024];
  int gid = blockIdx.x * 1024 + threadIdx.x;
  int v = (gid < n) ? cnt[gid] : 0;
  s[threadIdx.x] = v;
  __syncthreads();
#pragma unroll
  for (int off = 1; off < 1024; off <<= 1) {
    int t = (threadIdx.x >= off) ? s[threadIdx.x - off] : 0;
    __syncthreads();
    s[threadIdx.x] += t;
    __syncthreads();
  }
  if (gid < n) indptr[gid] = s[threadIdx.x] - v;
  if (threadIdx.x == 1023) chunkSums[blockIdx.x] = s[1023];
}

__global__ void scan_chunks(int* __restrict__ chunkSums, int nChunks) {
  if (threadIdx.x == 0 && blockIdx.x == 0) {
    int acc = 0;
    for (int i = 0; i < nChunks; ++i) { int t = chunkSums[i]; chunkSums[i] = acc; acc += t; }
  }
}

__global__ void add_offsets(int* __restrict__ indptr, const int* __restrict__ chunkSums,
                            int n, int total) {
  int gid = blockIdx.x * 256 + threadIdx.x;
  if (gid < n) indptr[gid] += chunkSums[gid >> 10];
  if (gid == 0) indptr[n] = total;
}

__global__ void build_csr(const int* __restrict__ row, const int* __restrict__ col,
                          const int* __restrict__ indptr, int* __restrict__ cursor,
                          int* __restrict__ srcSorted, int E) {
  int e = blockIdx.x * 256 + threadIdx.x;
  if (e < E) {
    int c = col[e];
    int p = indptr[c] + atomicAdd(&cursor[c], 1);
    srcSorted[p] = row[e];
  }
}

// ---------------------------------------------------------------------------
// converts
// ---------------------------------------------------------------------------
// x [N][256] f32 -> chunk-major bf16 Xc[8][M_PAD][32]
__global__ void cvt_chunked(const float* __restrict__ in, ushort* __restrict__ Xc, int n4) {
  int i = blockIdx.x * 256 + threadIdx.x;
  if (i < n4) {
    int n = i >> 6;
    int fq = (i & 63) * 4;
    int c = fq >> 5;
    int fi = fq & 31;
    float4 v = *(const float4*)(in + (size_t)i * 4);
    ushort4 o = make_ushort4(f2b(v.x), f2b(v.y), f2b(v.z), f2b(v.w));
    *(ushort4*)(Xc + (size_t)c * CH_STRIDE + (size_t)n * 32 + fi) = o;
  }
}

template <int LOGK>
__global__ void wT_kernel(const float* __restrict__ W, ushort* __restrict__ WT, int N, int total) {
  int i = blockIdx.x * 256 + threadIdx.x;
  if (i < total) {
    int k = i & ((1 << LOGK) - 1);
    int n = i >> LOGK;
    WT[i] = f2b(W[(size_t)k * N + n]);
  }
}

// ---------------------------------------------------------------------------
// chunked gather-aggregate. grid = 8 * ceil(N/4) blocks; c = bid%8 (XCD pin),
// 4 waves/block, one node per wave. 4 edge-slots x 16 lanes x 2 features.
// EPI=false: out bf16 node-major agg [M_PAD][256]; + mask gen when g%8==c.
// EPI=true : bias/relu/threefry-drop, out fp32 [N][256].
// ---------------------------------------------------------------------------
template <bool EPI>
__global__ __launch_bounds__(256) void gather_chunk(const ushort* __restrict__ Xc,
                                                    const int* __restrict__ indptr,
                                                    const int* __restrict__ srcS,
                                                    const float* __restrict__ dinv,
                                                    const float* __restrict__ bias,
                                                    void* __restrict__ outp,
                                                    unsigned char* __restrict__ maskOut,
                                                    unsigned kk0, unsigned kk1, int N) {
  const int bid = blockIdx.x;
  const int c = bid & 7;
  const int g = bid >> 3;
  const int wv = threadIdx.x >> 6;
  const int lane = threadIdx.x & 63;
  const int n = g * 4 + wv;
  if (n >= N) return;
  const int s = lane >> 4;    // edge slot 0..3
  const int fp = lane & 15;   // feature pair (2*fp, 2*fp+1)
  const int beg = __builtin_amdgcn_readfirstlane(indptr[n]);
  const int end = __builtin_amdgcn_readfirstlane(indptr[n + 1]);
  const float dc = dinv[n];
  const ushort* chunk = Xc + (size_t)c * CH_STRIDE;

  float ax = 0.f, ay = 0.f;
  if (s == 0) {  // self-loop term
    unsigned u = *(const unsigned*)(chunk + (size_t)n * 32 + fp * 2);
    ax = b2f_lo(u) * dc;
    ay = b2f_hi(u) * dc;
  }
  for (int i = beg + s; i < end; i += 4) {
    int r = __builtin_nontemporal_load(srcS + i);
    float w = dinv[r];
    unsigned u = *(const unsigned*)(chunk + (size_t)r * 32 + fp * 2);
    ax += b2f_lo(u) * w;
    ay += b2f_hi(u) * w;
  }
  ax += __shfl_xor(ax, 16); ay += __shfl_xor(ay, 16);
  ax += __shfl_xor(ax, 32); ay += __shfl_xor(ay, 32);
  ax *= dc; ay *= dc;

  if (!EPI) {
    if (s == 0) {
      unsigned o = (unsigned)f2b(ax) | ((unsigned)f2b(ay) << 16);
      *(unsigned*)((ushort*)outp + (size_t)n * 256 + c * 32 + fp * 2) = o;
    }
    // layer-1 dropout mask: exactly one chunk-block per node-group does it
    if ((g & 7) == c) {
      unsigned gl = (unsigned)n * 64u + (unsigned)lane;
      unsigned eb = gl * 8u;
      unsigned byte = 0;
#pragma unroll
      for (int j = 0; j < 8; ++j) {
        U2 r = threefry2x32(kk0, kk1, 0u, eb + (unsigned)j);
        byte |= (((r.a ^ r.b) >> 31) & 1u) << j;
      }
      maskOut[gl] = (unsigned char)byte;
    }
  } else {
    // redistribute the 32 features to 32 lanes for the threefry epilogue
    float a = __shfl(ax, lane >> 1);
    float b = __shfl(ay, lane >> 1);
    float v = (lane & 1) ? b : a;
    if (lane < 32) {
      int f = c * 32 + lane;
      v = drop_apply(v + bias[f], (unsigned)n * 256u + (unsigned)f, kk0, kk1);
      ((float*)outp)[(size_t)n * 256 + f] = v;
    }
  }
}

// ---------------------------------------------------------------------------
// bf16 MFMA GEMM: C[M,N] = A[M,K] @ BT[N,K]^T.  128x128 tile, BK=64, 4 waves,
// double-buffered LDS with prefetch, XOR-swizzled stage/read, coalesced bf16
// C-store via LDS transpose. EPI: bias+relu+bitmask dropout.
// CHUNK_OUT: store C chunk-major [8][M_PAD][32].
// ---------------------------------------------------------------------------
template <bool EPI, bool CHUNK_OUT>
__global__ __launch_bounds__(256) void gemm_bf16(const ushort* __restrict__ A,
                                                 const ushort* __restrict__ BT,
                                                 ushort* __restrict__ C,
                                                 int M, int K, int N,
                                                 const float* __restrict__ bias,
                                                 const unsigned char* __restrict__ mask) {
  __shared__ __align__(16) ushort lds[4 * 128 * 64];  // A0 A1 B0 B1 (16KB each)
  const int tid = threadIdx.x;
  const int lane = tid & 63;
  const int wv = tid >> 6;
  const int wr = wv >> 1, wc = wv & 1;
  const int bm = blockIdx.x * 128;
  const int bn = blockIdx.y * 128;

  f32x4 acc[4][4] = {};
  const int xorv = (lane & 7) << 4;

  auto stage = [&](int buf, int k0) {
#pragma unroll
    for (int l = 0; l < 4; ++l) {
      int cid = l * 256 + tid;
      int row = cid >> 3;
      int kcol = ((cid & 7) ^ (row & 7)) * 8;
      gload16(A + (size_t)(bm + row) * K + k0 + kcol, (void*)(lds + buf * 8192 + cid * 8));
      gload16(BT + (size_t)(bn + row) * K + k0 + kcol, (void*)(lds + (2 + buf) * 8192 + cid * 8));
    }
  };

  const int nt = K >> 6;
  stage(0, 0);
  __syncthreads();
  int cur = 0;
  for (int t = 0; t < nt; ++t) {
    if (t + 1 < nt) stage(cur ^ 1, (t + 1) << 6);
    const char* Ab = (const char*)(lds + cur * 8192);
    const char* Bb = (const char*)(lds + (2 + cur) * 8192);
#pragma unroll
    for (int ks = 0; ks < 2; ++ks) {
      bf16x8 af[4], bf[4];
      const int kb = (ks * 64 + (lane >> 4) * 16) ^ xorv;
#pragma unroll
      for (int i = 0; i < 4; ++i) {
        int arow = wr * 64 + i * 16 + (lane & 15);
        af[i] = *(const bf16x8*)(Ab + arow * 128 + kb);
        int brow = wc * 64 + i * 16 + (lane & 15);
        bf[i] = *(const bf16x8*)(Bb + brow * 128 + kb);
      }
#pragma unroll
      for (int m = 0; m < 4; ++m)
#pragma unroll
        for (int n = 0; n < 4; ++n)
          acc[m][n] = __builtin_amdgcn_mfma_f32_16x16x32_bf16(af[m], bf[n], acc[m][n], 0, 0, 0);
    }
    __syncthreads();
    cur ^= 1;
  }

  // ---- epilogue: acc -> (bias/relu/drop) -> bf16 -> LDS [128][132] -> store
  ushort* Csm = (ushort*)lds;
  const int rowoff = wr * 64 + ((lane >> 4) << 2);
  const int coloff = wc * 64 + (lane & 15);
  float bias_v[4];
  if (EPI) {
#pragma unroll
    for (int n = 0; n < 4; ++n) bias_v[n] = bias[bn + coloff + n * 16];
  }
#pragma unroll
  for (int m = 0; m < 4; ++m) {
#pragma unroll
    for (int r = 0; r < 4; ++r) {
      int lrow = rowoff + m * 16 + r;
      unsigned long long mk = 0;
      if (EPI) {
        unsigned base = (unsigned)(bm + lrow) * (unsigned)N + (unsigned)(bn + wc * 64);
        mk = *(const unsigned long long*)(mask + (base >> 3));
      }
#pragma unroll
      for (int n = 0; n < 4; ++n) {
        float v = acc[m][n][r];
        if (EPI) {
          v = fmaxf(v + bias_v[n], 0.f);
          v = ((mk >> ((lane & 15) + n * 16)) & 1ull) ? 0.f : v * 2.0f;
        }
        Csm[lrow * 132 + coloff + n * 16] = f2b(v);
      }
    }
  }
  __syncthreads();
  {
    int row = tid >> 1, ch = (tid & 1) * 64;
    const ushort* src = Csm + row * 132 + ch;
    if (CHUNK_OUT) {
      int gc = bn + ch;
#pragma unroll
      for (int p = 0; p < 2; ++p) {
        int c = (gc >> 5) + p;
        ushort* dst = C + (size_t)c * CH_STRIDE + (size_t)(bm + row) * 32;
#pragma unroll
        for (int j = 0; j < 4; ++j)
          *(bf16x8*)(dst + j * 8) = *(const bf16x8*)(src + p * 32 + j * 8);
      }
    } else {
      ushort* dst = C + (size_t)(bm + row) * N + bn + ch;
#pragma unroll
      for (int j = 0; j < 8; ++j)
        *(bf16x8*)(dst + j * 8) = *(const bf16x8*)(src + j * 8);
    }
  }
}

// ---------------------------------------------------------------------------
extern "C" void kernel_launch(void* const* d_in, const int* in_sizes, int n_in,
                              void* d_out, int out_size, void* d_ws, size_t ws_size,
                              hipStream_t stream) {
  const float* x  = (const float*)d_in[0];
  const int*   ei = (const int*)d_in[1];
  const float* W1 = (const float*)d_in[2];
  const float* b1 = (const float*)d_in[3];
  const float* W2 = (const float*)d_in[4];
  const float* b2 = (const float*)d_in[5];
  float* out = (float*)d_out;
  (void)in_sizes; (void)n_in; (void)out_size; (void)ws_size;

  const int* row = ei;
  const int* col = ei + N_EDGES;

  // workspace layout (bytes)
  char* ws = (char*)d_ws;
  float*  dinv      = (float*) (ws);                         // 200 KB
  int*    cnt       = (int*)   (ws + (1u << 18));            // 200 KB
  int*    indptr    = (int*)   (ws + (2u << 18));            // 200 KB + 4
  int*    cursor    = (int*)   (ws + (3u << 18));            // 200 KB
  int*    chunkSums = (int*)   (ws + (1u << 20));            // tiny
  int*    srcSorted = (int*)   (ws + (1u << 20) + (1u << 16)); // 3.2 MB
  ushort* W1T       = (ushort*)(ws + 5u  * (1u << 20));      // 256 KB [512][256]
  ushort* W2T       = (ushort*)(ws + 5u  * (1u << 20) + (1u << 19)); // 256 KB
  unsigned char* mask1 = (unsigned char*)(ws + 6u * (1u << 20)); // 3.21 MB
  ushort* x16c      = (ushort*)(ws + 10u * (1u << 20));      // 25.6 MB [8][M_PAD][32]
  ushort* aggB      = (ushort*)(ws + 36u * (1u << 20));      // 25.6 MB [M_PAD][256]
  ushort* h         = (ushort*)(ws + 64u * (1u << 20));      // 51.2 MB [M_PAD][512]
  ushort* hw2c      = (ushort*)(ws + 116u* (1u << 20));      // 25.6 MB [8][M_PAD][32]

  constexpr U2 K1 = threefry2x32(0u, 42u, 0u, 0u);
  constexpr U2 K2 = threefry2x32(0u, 42u, 0u, 1u);

  // ---- CSR build ----
  hipMemsetAsync(cnt, 0, N_NODES * sizeof(int), stream);
  hipMemsetAsync(cursor, 0, N_NODES * sizeof(int), stream);
  deg_kernel<<<(N_EDGES + 255) / 256, 256, 0, stream>>>(col, cnt, N_EDGES);
  dinv_kernel<<<(N_NODES + 255) / 256, 256, 0, stream>>>(cnt, dinv, N_NODES);
  const int nChunks = (N_NODES + 1023) / 1024;
  scan_local<<<nChunks, 1024, 0, stream>>>(cnt, indptr, chunkSums, N_NODES);
  scan_chunks<<<1, 64, 0, stream>>>(chunkSums, nChunks);
  add_offsets<<<(N_NODES + 255) / 256, 256, 0, stream>>>(indptr, chunkSums, N_NODES, N_EDGES);
  build_csr<<<(N_EDGES + 255) / 256, 256, 0, stream>>>(row, col, indptr, cursor, srcSorted, N_EDGES);

  // ---- converts ----
  cvt_chunked<<<(N_NODES * IN_C / 4 + 255) / 256, 256, 0, stream>>>(x, x16c, N_NODES * IN_C / 4);
  wT_kernel<8><<<(IN_C * HID_C + 255) / 256, 256, 0, stream>>>(W1, W1T, HID_C, IN_C * HID_C);
  wT_kernel<9><<<(HID_C * OUT_C + 255) / 256, 256, 0, stream>>>(W2, W2T, OUT_C, HID_C * OUT_C);
  hipMemsetAsync(aggB + (size_t)N_NODES * IN_C, 0, (size_t)(M_PAD - N_NODES) * IN_C * 2, stream);

  const int gatherGrid = 8 * ((N_NODES + 3) / 4);

  // ---- layer 1 ----
  gather_chunk<false><<<gatherGrid, 256, 0, stream>>>(
      x16c, indptr, srcSorted, dinv, nullptr, aggB, mask1, K1.a, K1.b, N_NODES);
  gemm_bf16<true, false><<<dim3(M_PAD / 128, HID_C / 128), 256, 0, stream>>>(
      aggB, W1T, h, M_PAD, IN_C, HID_C, b1, mask1);

  // ---- layer 2 ----
  gemm_bf16<false, true><<<dim3(M_PAD / 128, OUT_C / 128), 256, 0, stream>>>(
      h, W2T, hw2c, M_PAD, HID_C, OUT_C, nullptr, nullptr);
  gather_chunk<true><<<gatherGrid, 256, 0, stream>>>(
      hw2c, indptr, srcSorted, dinv, b2, out, nullptr, K2.a, K2.b, N_NODES);
}

// Round 6
// 333.366 us; speedup vs baseline: 2.2926x; 2.2926x over previous
//
#include <hip/hip_runtime.h>
#include <stdint.h>

// ---------------------------------------------------------------------------
// GCN: agg1 = A_hat x (bf16 gather, 8-deep MLP, + layer1 dropout-mask gen)
//      h    = relu+drop(agg1 W1 + b1)   (MFMA GEMM, mask from bitmask)
//      hw2  = h W2                      (MFMA GEMM)
//      out  = relu+drop(A_hat hw2 + b2) (gather + inline threefry epilogue)
// CSR carries fused (src, weight) pairs so the gather chain is pair->row->FMA.
// ---------------------------------------------------------------------------

#define N_NODES 50000
#define N_EDGES 800000
#define M_PAD   50048   // 391 * 128
#define IN_C 256
#define HID_C 512
#define OUT_C 256

typedef __attribute__((ext_vector_type(8))) short bf16x8;
typedef __attribute__((ext_vector_type(4))) float f32x4;

struct U2 { unsigned a, b; };

__host__ __device__ constexpr unsigned rotl32(unsigned x, int d) {
  return (x << d) | (x >> (32 - d));
}

#define TF_ROUND(r) { x0 += x1; x1 = rotl32(x1, (r)); x1 ^= x0; }

__host__ __device__ constexpr U2 threefry2x32(unsigned k0, unsigned k1,
                                              unsigned x0, unsigned x1) {
  unsigned ks2 = k0 ^ k1 ^ 0x1BD11BDAu;
  x0 += k0; x1 += k1;
  TF_ROUND(13) TF_ROUND(15) TF_ROUND(26) TF_ROUND(6)  x0 += k1;  x1 += ks2 + 1u;
  TF_ROUND(17) TF_ROUND(29) TF_ROUND(16) TF_ROUND(24) x0 += ks2; x1 += k0 + 2u;
  TF_ROUND(13) TF_ROUND(15) TF_ROUND(26) TF_ROUND(6)  x0 += k0;  x1 += k1 + 3u;
  TF_ROUND(17) TF_ROUND(29) TF_ROUND(16) TF_ROUND(24) x0 += k1;  x1 += ks2 + 4u;
  TF_ROUND(13) TF_ROUND(15) TF_ROUND(26) TF_ROUND(6)  x0 += ks2; x1 += k0 + 5u;
  return U2{x0, x1};
}

__device__ __forceinline__ float drop_apply(float v, unsigned idx, unsigned k0, unsigned k1) {
  v = fmaxf(v, 0.f);
  U2 r = threefry2x32(k0, k1, 0u, idx);
  unsigned bits = r.a ^ r.b;
  return (bits >> 31) ? 0.f : v * 2.0f;
}

__device__ __forceinline__ ushort f2b(float f) {  // RTNE
  unsigned u = __builtin_bit_cast(unsigned, f);
  unsigned r = (u + 0x7fffu + ((u >> 16) & 1u)) >> 16;
  return (ushort)r;
}
__device__ __forceinline__ float b2f(ushort h) {
  unsigned u = (unsigned)h << 16;
  return __builtin_bit_cast(float, u);
}

__device__ __forceinline__ void gload16(const void* g, void* l) {
  __builtin_amdgcn_global_load_lds(
      (const __attribute__((address_space(1))) void*)g,
      (__attribute__((address_space(3))) void*)l, 16, 0, 0);
}

// ---------------------------------------------------------------------------
// degree / dinv / scan / CSR build (CSR entry = {src, dinv[src]})
// ---------------------------------------------------------------------------
__global__ void deg_kernel(const int* __restrict__ col, int* __restrict__ cnt, int E) {
  int e = blockIdx.x * 256 + threadIdx.x;
  if (e < E) atomicAdd(&cnt[col[e]], 1);
}

__global__ void dinv_kernel(const int* __restrict__ cnt, float* __restrict__ dinv, int N) {
  int n = blockIdx.x * 256 + threadIdx.x;
  if (n < N) dinv[n] = rsqrtf((float)cnt[n] + 1.0f);
}

__global__ __launch_bounds__(1024) void scan_local(const int* __restrict__ cnt,
                                                   int* __restrict__ indptr,
                                                   int* __restrict__ chunkSums, int n) {
  __shared__ int s[1024];
  int gid = blockIdx.x * 1024 + threadIdx.x;
  int v = (gid < n) ? cnt[gid] : 0;
  s[threadIdx.x] = v;
  __syncthreads();
#pragma unroll
  for (int off = 1; off < 1024; off <<= 1) {
    int t = (threadIdx.x >= off) ? s[threadIdx.x - off] : 0;
    __syncthreads();
    s[threadIdx.x] += t;
    __syncthreads();
  }
  if (gid < n) indptr[gid] = s[threadIdx.x] - v;
  if (threadIdx.x == 1023) chunkSums[blockIdx.x] = s[1023];
}

__global__ void scan_chunks(int* __restrict__ chunkSums, int nChunks) {
  if (threadIdx.x == 0 && blockIdx.x == 0) {
    int acc = 0;
    for (int i = 0; i < nChunks; ++i) { int t = chunkSums[i]; chunkSums[i] = acc; acc += t; }
  }
}

__global__ void add_offsets(int* __restrict__ indptr, const int* __restrict__ chunkSums,
                            int n, int total) {
  int gid = blockIdx.x * 256 + threadIdx.x;
  if (gid < n) indptr[gid] += chunkSums[gid >> 10];
  if (gid == 0) indptr[n] = total;
}

__global__ void build_csr(const int* __restrict__ row, const int* __restrict__ col,
                          const int* __restrict__ indptr, int* __restrict__ cursor,
                          const float* __restrict__ dinv,
                          int2* __restrict__ srcW, int E) {
  int e = blockIdx.x * 256 + threadIdx.x;
  if (e < E) {
    int r = row[e];
    int c = col[e];
    int p = indptr[c] + atomicAdd(&cursor[c], 1);
    srcW[p] = make_int2(r, __builtin_bit_cast(int, dinv[r]));
  }
}

// ---------------------------------------------------------------------------
// converts
// ---------------------------------------------------------------------------
__global__ void cvt_f32_bf16(const float* __restrict__ in, ushort* __restrict__ out, int n4) {
  int i = blockIdx.x * 256 + threadIdx.x;
  if (i < n4) {
    float4 v = *(const float4*)(in + (size_t)i * 4);
    ushort4 o = make_ushort4(f2b(v.x), f2b(v.y), f2b(v.z), f2b(v.w));
    *(ushort4*)(out + (size_t)i * 4) = o;
  }
}

template <int LOGK>
__global__ void wT_kernel(const float* __restrict__ W, ushort* __restrict__ WT, int N, int total) {
  int i = blockIdx.x * 256 + threadIdx.x;
  if (i < total) {
    int k = i & ((1 << LOGK) - 1);
    int n = i >> LOGK;
    WT[i] = f2b(W[(size_t)k * N + n]);
  }
}

// ---------------------------------------------------------------------------
// gather-aggregate over CSR pairs, bf16 table [*,256], one wave per node.
// 8-deep unrolled main loop for MLP. EPI=false: bf16 out + layer-1 bitmask.
// EPI=true: bias/relu/inline-threefry-drop, fp32 out.
// ---------------------------------------------------------------------------
#define ROW_ACC(vv, ww)                                                        \
  { a0 += b2f((vv).x) * (ww); a1 += b2f((vv).y) * (ww);                        \
    a2 += b2f((vv).z) * (ww); a3 += b2f((vv).w) * (ww); }

template <bool EPI>
__global__ __launch_bounds__(256) void gather_agg16(const ushort* __restrict__ X,
                                                    const int* __restrict__ indptr,
                                                    const int2* __restrict__ srcW,
                                                    const float* __restrict__ dinv,
                                                    const float* __restrict__ bias,
                                                    void* __restrict__ outp,
                                                    unsigned char* __restrict__ maskOut,
                                                    unsigned kk0, unsigned kk1, int N) {
  int wid = (blockIdx.x * 256 + threadIdx.x) >> 6;
  int lane = threadIdx.x & 63;
  if (wid >= N) return;
  int beg = __builtin_amdgcn_readfirstlane(indptr[wid]);
  int end = __builtin_amdgcn_readfirstlane(indptr[wid + 1]);
  float dc = dinv[wid];
  const int f0 = lane * 4;
  ushort4 sv = *(const ushort4*)(X + (size_t)wid * 256 + f0);
  float a0 = b2f(sv.x) * dc, a1 = b2f(sv.y) * dc,
        a2 = b2f(sv.z) * dc, a3 = b2f(sv.w) * dc;

  int e = beg;
  for (; e + 8 <= end; e += 8) {
    int2 p0 = srcW[e + 0], p1 = srcW[e + 1], p2 = srcW[e + 2], p3 = srcW[e + 3];
    int2 p4 = srcW[e + 4], p5 = srcW[e + 5], p6 = srcW[e + 6], p7 = srcW[e + 7];
    ushort4 v0 = *(const ushort4*)(X + (size_t)p0.x * 256 + f0);
    ushort4 v1 = *(const ushort4*)(X + (size_t)p1.x * 256 + f0);
    ushort4 v2 = *(const ushort4*)(X + (size_t)p2.x * 256 + f0);
    ushort4 v3 = *(const ushort4*)(X + (size_t)p3.x * 256 + f0);
    ushort4 v4 = *(const ushort4*)(X + (size_t)p4.x * 256 + f0);
    ushort4 v5 = *(const ushort4*)(X + (size_t)p5.x * 256 + f0);
    ushort4 v6 = *(const ushort4*)(X + (size_t)p6.x * 256 + f0);
    ushort4 v7 = *(const ushort4*)(X + (size_t)p7.x * 256 + f0);
    ROW_ACC(v0, __builtin_bit_cast(float, p0.y));
    ROW_ACC(v1, __builtin_bit_cast(float, p1.y));
    ROW_ACC(v2, __builtin_bit_cast(float, p2.y));
    ROW_ACC(v3, __builtin_bit_cast(float, p3.y));
    ROW_ACC(v4, __builtin_bit_cast(float, p4.y));
    ROW_ACC(v5, __builtin_bit_cast(float, p5.y));
    ROW_ACC(v6, __builtin_bit_cast(float, p6.y));
    ROW_ACC(v7, __builtin_bit_cast(float, p7.y));
  }
  for (; e + 2 <= end; e += 2) {
    int2 p0 = srcW[e + 0], p1 = srcW[e + 1];
    ushort4 v0 = *(const ushort4*)(X + (size_t)p0.x * 256 + f0);
    ushort4 v1 = *(const ushort4*)(X + (size_t)p1.x * 256 + f0);
    ROW_ACC(v0, __builtin_bit_cast(float, p0.y));
    ROW_ACC(v1, __builtin_bit_cast(float, p1.y));
  }
  if (e < end) {
    int2 p0 = srcW[e];
    ushort4 v0 = *(const ushort4*)(X + (size_t)p0.x * 256 + f0);
    ROW_ACC(v0, __builtin_bit_cast(float, p0.y));
  }
  a0 *= dc; a1 *= dc; a2 *= dc; a3 *= dc;

  if (EPI) {
    unsigned base = (unsigned)wid * 256u + (unsigned)f0;
    a0 = drop_apply(a0 + bias[f0 + 0], base + 0, kk0, kk1);
    a1 = drop_apply(a1 + bias[f0 + 1], base + 1, kk0, kk1);
    a2 = drop_apply(a2 + bias[f0 + 2], base + 2, kk0, kk1);
    a3 = drop_apply(a3 + bias[f0 + 3], base + 3, kk0, kk1);
    *(float4*)((float*)outp + (size_t)wid * 256 + f0) = make_float4(a0, a1, a2, a3);
  } else {
    ushort4 o = make_ushort4(f2b(a0), f2b(a1), f2b(a2), f2b(a3));
    *(ushort4*)((ushort*)outp + (size_t)wid * 256 + f0) = o;
    // layer-1 dropout mask: this lane packs bits for h elements [gl*8, gl*8+8)
    unsigned gl = (unsigned)wid * 64u + (unsigned)lane;
    unsigned eb = gl * 8u;
    unsigned byte = 0;
#pragma unroll
    for (int j = 0; j < 8; ++j) {
      U2 r = threefry2x32(kk0, kk1, 0u, eb + (unsigned)j);
      byte |= (((r.a ^ r.b) >> 31) & 1u) << j;
    }
    maskOut[gl] = (unsigned char)byte;
  }
}

// ---------------------------------------------------------------------------
// bf16 MFMA GEMM: C[M,N] = A[M,K] @ BT[N,K]^T.  128x128 tile, BK=64, 4 waves,
// double-buffered LDS with prefetch, XOR-swizzled stage/read, coalesced bf16
// C-store via LDS transpose. EPI: bias+relu+bitmask dropout.
// ---------------------------------------------------------------------------
template <bool EPI>
__global__ __launch_bounds__(256) void gemm_bf16(const ushort* __restrict__ A,
                                                 const ushort* __restrict__ BT,
                                                 ushort* __restrict__ C,
                                                 int M, int K, int N,
                                                 const float* __restrict__ bias,
                                                 const unsigned char* __restrict__ mask) {
  __shared__ __align__(16) ushort lds[4 * 128 * 64];  // A0 A1 B0 B1 (16KB each)
  const int tid = threadIdx.x;
  const int lane = tid & 63;
  const int wv = tid >> 6;
  const int wr = wv >> 1, wc = wv & 1;
  const int bm = blockIdx.x * 128;
  const int bn = blockIdx.y * 128;

  f32x4 acc[4][4] = {};
  const int xorv = (lane & 7) << 4;

  auto stage = [&](int buf, int k0) {
#pragma unroll
    for (int l = 0; l < 4; ++l) {
      int cid = l * 256 + tid;
      int row = cid >> 3;
      int kcol = ((cid & 7) ^ (row & 7)) * 8;
      gload16(A + (size_t)(bm + row) * K + k0 + kcol, (void*)(lds + buf * 8192 + cid * 8));
      gload16(BT + (size_t)(bn + row) * K + k0 + kcol, (void*)(lds + (2 + buf) * 8192 + cid * 8));
    }
  };

  const int nt = K >> 6;
  stage(0, 0);
  __syncthreads();
  int cur = 0;
  for (int t = 0; t < nt; ++t) {
    if (t + 1 < nt) stage(cur ^ 1, (t + 1) << 6);
    const char* Ab = (const char*)(lds + cur * 8192);
    const char* Bb = (const char*)(lds + (2 + cur) * 8192);
#pragma unroll
    for (int ks = 0; ks < 2; ++ks) {
      bf16x8 af[4], bf[4];
      const int kb = (ks * 64 + (lane >> 4) * 16) ^ xorv;
#pragma unroll
      for (int i = 0; i < 4; ++i) {
        int arow = wr * 64 + i * 16 + (lane & 15);
        af[i] = *(const bf16x8*)(Ab + arow * 128 + kb);
        int brow = wc * 64 + i * 16 + (lane & 15);
        bf[i] = *(const bf16x8*)(Bb + brow * 128 + kb);
      }
#pragma unroll
      for (int m = 0; m < 4; ++m)
#pragma unroll
        for (int n = 0; n < 4; ++n)
          acc[m][n] = __builtin_amdgcn_mfma_f32_16x16x32_bf16(af[m], bf[n], acc[m][n], 0, 0, 0);
    }
    __syncthreads();
    cur ^= 1;
  }

  // ---- epilogue: acc -> (bias/relu/drop) -> bf16 -> LDS [128][132] -> store
  ushort* Csm = (ushort*)lds;
  const int rowoff = wr * 64 + ((lane >> 4) << 2);
  const int coloff = wc * 64 + (lane & 15);
  float bias_v[4];
  if (EPI) {
#pragma unroll
    for (int n = 0; n < 4; ++n) bias_v[n] = bias[bn + coloff + n * 16];
  }
#pragma unroll
  for (int m = 0; m < 4; ++m) {
#pragma unroll
    for (int r = 0; r < 4; ++r) {
      int lrow = rowoff + m * 16 + r;
      unsigned long long mk = 0;
      if (EPI) {
        unsigned base = (unsigned)(bm + lrow) * (unsigned)N + (unsigned)(bn + wc * 64);
        mk = *(const unsigned long long*)(mask + (base >> 3));
      }
#pragma unroll
      for (int n = 0; n < 4; ++n) {
        float v = acc[m][n][r];
        if (EPI) {
          v = fmaxf(v + bias_v[n], 0.f);
          v = ((mk >> ((lane & 15) + n * 16)) & 1ull) ? 0.f : v * 2.0f;
        }
        Csm[lrow * 132 + coloff + n * 16] = f2b(v);
      }
    }
  }
  __syncthreads();
  {
    int row = tid >> 1, ch = (tid & 1) * 64;
    const ushort* src = Csm + row * 132 + ch;
    ushort* dst = C + (size_t)(bm + row) * N + bn + ch;
#pragma unroll
    for (int j = 0; j < 8; ++j)
      *(bf16x8*)(dst + j * 8) = *(const bf16x8*)(src + j * 8);
  }
}

// ---------------------------------------------------------------------------
extern "C" void kernel_launch(void* const* d_in, const int* in_sizes, int n_in,
                              void* d_out, int out_size, void* d_ws, size_t ws_size,
                              hipStream_t stream) {
  const float* x  = (const float*)d_in[0];
  const int*   ei = (const int*)d_in[1];
  const float* W1 = (const float*)d_in[2];
  const float* b1 = (const float*)d_in[3];
  const float* W2 = (const float*)d_in[4];
  const float* b2 = (const float*)d_in[5];
  float* out = (float*)d_out;
  (void)in_sizes; (void)n_in; (void)out_size; (void)ws_size;

  const int* row = ei;
  const int* col = ei + N_EDGES;

  // workspace layout (bytes)
  char* ws = (char*)d_ws;
  float*  dinv      = (float*) (ws);                           // 200 KB
  int*    cnt       = (int*)   (ws + (1u << 18));              // 200 KB
  int*    indptr    = (int*)   (ws + (2u << 18));              // 200 KB + 4
  int*    cursor    = (int*)   (ws + (3u << 18));              // 200 KB
  int*    chunkSums = (int*)   (ws + (1u << 20));              // tiny
  int2*   srcW      = (int2*)  (ws + 2u * (1u << 20));         // 6.4 MB
  ushort* W1T       = (ushort*)(ws + 9u * (1u << 20));         // 256 KB [512][256]
  ushort* W2T       = (ushort*)(ws + 9u * (1u << 20) + (1u << 19)); // 256 KB
  unsigned char* mask1 = (unsigned char*)(ws + 10u * (1u << 20)); // 3.21 MB
  ushort* x16       = (ushort*)(ws + 14u * (1u << 20));        // 25.6 MB [50000][256]
  ushort* aggB      = (ushort*)(ws + 40u * (1u << 20));        // 25.6 MB [M_PAD][256]
  ushort* h         = (ushort*)(ws + 66u * (1u << 20));        // 51.2 MB [M_PAD][512]
  ushort* hw2       = (ushort*)(ws + 118u* (1u << 20));        // 25.6 MB [M_PAD][256]

  constexpr U2 K1 = threefry2x32(0u, 42u, 0u, 0u);
  constexpr U2 K2 = threefry2x32(0u, 42u, 0u, 1u);

  // ---- CSR build ----
  hipMemsetAsync(cnt, 0, N_NODES * sizeof(int), stream);
  hipMemsetAsync(cursor, 0, N_NODES * sizeof(int), stream);
  deg_kernel<<<(N_EDGES + 255) / 256, 256, 0, stream>>>(col, cnt, N_EDGES);
  dinv_kernel<<<(N_NODES + 255) / 256, 256, 0, stream>>>(cnt, dinv, N_NODES);
  const int nChunks = (N_NODES + 1023) / 1024;
  scan_local<<<nChunks, 1024, 0, stream>>>(cnt, indptr, chunkSums, N_NODES);
  scan_chunks<<<1, 64, 0, stream>>>(chunkSums, nChunks);
  add_offsets<<<(N_NODES + 255) / 256, 256, 0, stream>>>(indptr, chunkSums, N_NODES, N_EDGES);
  build_csr<<<(N_EDGES + 255) / 256, 256, 0, stream>>>(row, col, indptr, cursor, dinv, srcW, N_EDGES);

  // ---- converts ----
  cvt_f32_bf16<<<(N_NODES * IN_C / 4 + 255) / 256, 256, 0, stream>>>(x, x16, N_NODES * IN_C / 4);
  wT_kernel<8><<<(IN_C * HID_C + 255) / 256, 256, 0, stream>>>(W1, W1T, HID_C, IN_C * HID_C);
  wT_kernel<9><<<(HID_C * OUT_C + 255) / 256, 256, 0, stream>>>(W2, W2T, OUT_C, HID_C * OUT_C);
  hipMemsetAsync(aggB + (size_t)N_NODES * IN_C, 0, (size_t)(M_PAD - N_NODES) * IN_C * 2, stream);

  // ---- layer 1 ----
  gather_agg16<false><<<(N_NODES + 3) / 4, 256, 0, stream>>>(
      x16, indptr, srcW, dinv, nullptr, aggB, mask1, K1.a, K1.b, N_NODES);
  gemm_bf16<true><<<dim3(M_PAD / 128, HID_C / 128), 256, 0, stream>>>(
      aggB, W1T, h, M_PAD, IN_C, HID_C, b1, mask1);

  // ---- layer 2 ----
  gemm_bf16<false><<<dim3(M_PAD / 128, OUT_C / 128), 256, 0, stream>>>(
      h, W2T, hw2, M_PAD, HID_C, OUT_C, nullptr, nullptr);
  gather_agg16<true><<<(N_NODES + 3) / 4, 256, 0, stream>>>(
      hw2, indptr, srcW, dinv, b2, out, nullptr, K2.a, K2.b, N_NODES);
}